// Round 16
// baseline (279.847 us; speedup 1.0000x reference)
//
#include <hip/hip_runtime.h>

typedef _Float16 f16;
typedef _Float16 h4 __attribute__((ext_vector_type(4)));
typedef _Float16 h8 __attribute__((ext_vector_type(8)));
typedef float f4 __attribute__((ext_vector_type(4)));

typedef const __attribute__((address_space(1))) char gchar;
typedef __attribute__((address_space(3))) char lchar;

#define B_ 4
#define S_ 2048
#define D_ 1024
#define H_ 1024

template <int N>
__device__ __forceinline__ void vmwait() {
  if constexpr (N == 0) asm volatile("s_waitcnt vmcnt(0)" ::: "memory");
  else if constexpr (N == 6) asm volatile("s_waitcnt vmcnt(6)" ::: "memory");
  else if constexpr (N == 16) asm volatile("s_waitcnt vmcnt(16)" ::: "memory");
}

// ---------------- cast x1,x2,x3,Wv f32->f16 : 16 elems/thread, exact grid ----------------
__global__ __launch_bounds__(256) void cast_x(
    const float* __restrict__ x1, const float* __restrict__ x2, const float* __restrict__ x3,
    const float* __restrict__ wv,
    f16* __restrict__ o1, f16* __restrict__ o2, f16* __restrict__ o3, f16* __restrict__ ow) {
  const long g = blockIdx.x * 256L + threadIdx.x;
  const float* in;
  f16* out;
  long off;
  if (g < (3L << 19)) {
    const int w = (int)(g >> 19);
    off = (g & ((1L << 19) - 1)) * 16;
    in = w == 0 ? x1 : (w == 1 ? x2 : x3);
    out = w == 0 ? o1 : (w == 1 ? o2 : o3);
  } else {
    off = (g - (3L << 19)) * 16;
    in = wv;
    out = ow;
  }
  float4 a = *(const float4*)(in + off);
  float4 b = *(const float4*)(in + off + 4);
  float4 c = *(const float4*)(in + off + 8);
  float4 d = *(const float4*)(in + off + 12);
  h8 o0, o1v;
  o0[0] = (f16)a.x; o0[1] = (f16)a.y; o0[2] = (f16)a.z; o0[3] = (f16)a.w;
  o0[4] = (f16)b.x; o0[5] = (f16)b.y; o0[6] = (f16)b.z; o0[7] = (f16)b.w;
  o1v[0] = (f16)c.x; o1v[1] = (f16)c.y; o1v[2] = (f16)c.z; o1v[3] = (f16)c.w;
  o1v[4] = (f16)d.x; o1v[5] = (f16)d.y; o1v[6] = (f16)d.z; o1v[7] = (f16)d.w;
  *(h8*)(out + off) = o0;
  *(h8*)(out + off + 8) = o1v;
}

// ---------------- transpose-cast Wq, Wk ----------------
__global__ __launch_bounds__(256) void wtrans(const float* __restrict__ wq,
                                              const float* __restrict__ wk,
                                              f16* __restrict__ oq, f16* __restrict__ ok) {
  __shared__ float t[32][33];
  const int bx = blockIdx.x;
  const float* in = (bx >> 10) ? wk : wq;
  f16* out = (bx >> 10) ? ok : oq;
  const int tile = bx & 1023;
  const int tr = tile >> 5, tc = tile & 31;
  const int tid = threadIdx.x;
  {
    const int r = tid >> 3, c4 = (tid & 7) * 4;
    float4 v = *(const float4*)(in + (long)(tr * 32 + r) * 1024 + tc * 32 + c4);
    t[r][c4] = v.x; t[r][c4 + 1] = v.y; t[r][c4 + 2] = v.z; t[r][c4 + 3] = v.w;
  }
  __syncthreads();
  {
    const int rr = tid >> 3, cc4 = (tid & 7) * 4;
    h4 o;
    o[0] = (f16)t[cc4][rr]; o[1] = (f16)t[cc4 + 1][rr];
    o[2] = (f16)t[cc4 + 2][rr]; o[3] = (f16)t[cc4 + 3][rr];
    *(h4*)(out + (long)(tc * 32 + rr) * 1024 + tr * 32 + cc4) = o;
  }
}

// ---------------- PROJ GEMM: C = A * B^T, 2-slot, syncthreads drain ----------
// OUT_MODE 1: f16 C[m*N+n] (+bz*sC)   OUT_MODE 2: f16 V^T per-batch
#define TILE 128
#define BK 32

template <int OUT_MODE>
__global__ __launch_bounds__(256) void gemm_abt(const f16* __restrict__ A,
                                                const f16* __restrict__ Bm,
                                                void* __restrict__ C,
                                                int M, int N, int K,
                                                long sA, long sB, long sC) {
  const int bz = blockIdx.z;
  A += (long)bz * sA;
  Bm += (long)bz * sB;

  __shared__ __align__(16) f16 lA[2][TILE * BK];
  __shared__ __align__(16) f16 lB[2][TILE * BK];

  const int tid = threadIdx.x;
  const int lane = tid & 63;
  const int w = tid >> 6;
  const int wr = w >> 1, wc = w & 1;
  const int m0 = blockIdx.x * TILE;
  const int n0 = blockIdx.y * TILE;

  const int lr = lane >> 2;
  const int lc = (lane & 3) * 8;
  const f16* Abase = A + (long)(m0 + lr) * K + lc;
  const f16* Bbase = Bm + (long)(n0 + lr) * K + lc;

  const int fr = lane & 15;
  const int kg = (lane >> 4) * 8;

  f4 acc[4][4] = {};

  auto STAGE = [&](int buf, int k0) {
#pragma unroll
    for (int c = 0; c < 2; ++c) {
      const int br = w * 32 + c * 16;
      __builtin_amdgcn_global_load_lds(
          (gchar*)(Abase + (long)br * K + k0),
          (lchar*)&lA[buf][br * BK], 16, 0, 0);
      __builtin_amdgcn_global_load_lds(
          (gchar*)(Bbase + (long)br * K + k0),
          (lchar*)&lB[buf][br * BK], 16, 0, 0);
    }
  };

  STAGE(0, 0);
  __syncthreads();

  int cur = 0;
  for (int k0 = 0; k0 < K; k0 += BK) {
    if (k0 + BK < K) STAGE(cur ^ 1, k0 + BK);

    h8 af[4], bf[4];
#pragma unroll
    for (int i = 0; i < 4; ++i) {
      af[i] = *(const h8*)&lA[cur][(wr * 64 + i * 16 + fr) * BK + kg];
      bf[i] = *(const h8*)&lB[cur][(wc * 64 + i * 16 + fr) * BK + kg];
    }
#pragma unroll
    for (int mi = 0; mi < 4; ++mi)
#pragma unroll
      for (int ni = 0; ni < 4; ++ni)
        acc[mi][ni] = __builtin_amdgcn_mfma_f32_16x16x32_f16(af[mi], bf[ni], acc[mi][ni], 0, 0, 0);

    __syncthreads();
    cur ^= 1;
  }

  const int fq = (lane >> 4) * 4;
#pragma unroll
  for (int mi = 0; mi < 4; ++mi) {
#pragma unroll
    for (int ni = 0; ni < 4; ++ni) {
#pragma unroll
      for (int i = 0; i < 4; ++i) {
        const int row = m0 + wr * 64 + mi * 16 + fq + i;
        const int col = n0 + wc * 64 + ni * 16 + fr;
        const float val = acc[mi][ni][i];
        if constexpr (OUT_MODE == 1) {
          f16* Cp = (f16*)C + (long)bz * sC;
          Cp[(long)row * N + col] = (f16)val;
        } else {
          f16* Cp = (f16*)C;
          const int b = row >> 11, sr = row & 2047;
          Cp[((long)b * N + col) * 2048 + sr] = (f16)val;
        }
      }
    }
  }
}

// ---------- 256x256 SCORES GEMM: BK=32, 4-slot ring (128 KiB), counted vmcnt(16) ----------
// 4 waves as 2x2; per-wave C = 128x128 (8x8 frags, 256 AGPR) -> 64 MFMA per K-step per wave.
// Slot = A 256x32 + B 256x32 = 32 KiB; 4 slots = 128 KiB -> 1 block/CU, grid 256 = 1/CU exact.
// Ring: tile t in slot t&3; iter t stages tile t+3 into slot of t-1 (reads done at t-1's end
// barrier). 8 loads/tile; vmcnt(16) retires tile t+1 (t+2,t+3 in flight). Involution swizzle
// as gemm128w. Epilogue: U = exp(val*scale + mask) -> f16, row partials atomicAdd'ed into rs.
__global__ __launch_bounds__(256, 1) void gemm256s(const f16* __restrict__ A,
                                                   const f16* __restrict__ Bm,
                                                   f16* __restrict__ C,
                                                   const float* __restrict__ mask,
                                                   float* __restrict__ rs,
                                                   int N, int K,
                                                   long sA, long sB, long sC,
                                                   int gx, int gy) {
  extern __shared__ __align__(16) f16 smem[];  // 4 * 16384 f16 = 131072 B

  const int cpx = gridDim.x >> 3;
  const int wgid = (blockIdx.x & 7) * cpx + (blockIdx.x >> 3);
  const int by = wgid % gy;
  const int bx = (wgid / gy) % gx;
  const int bz = wgid / (gy * gx);
  A += (long)bz * sA;
  Bm += (long)bz * sB;
  const int m0 = bx * 256, n0 = by * 256;

  const int tid = threadIdx.x;
  const int lane = tid & 63;
  const int w = tid >> 6;
  const int wm = w >> 1, wn = w & 1;   // 2x2 waves; per-wave 128 rows x 128 cols
  const int fr = lane & 15;
  const int g = lane >> 4;

  const int r0 = tid >> 2;             // staging row within 64-row chunk
  const int s = tid & 3;

  // 4 chunk-calls per matrix per tile (256 rows); LDS dest linear, global src pre-swizzled
  auto STAGE = [&](int sl, int t) {
    const long k0 = (long)t * 32;
#pragma unroll
    for (int c = 0; c < 4; ++c) {
      const int row = c * 64 + r0;
      const int scol = (s ^ ((row >> 1) & 3)) * 8;
      __builtin_amdgcn_global_load_lds(
          (gchar*)(A + (long)(m0 + row) * K + k0 + scol),
          (lchar*)(smem + sl * 16384 + c * 2048 + tid * 8), 16, 0, 0);
      __builtin_amdgcn_global_load_lds(
          (gchar*)(Bm + (long)(n0 + row) * K + k0 + scol),
          (lchar*)(smem + sl * 16384 + 8192 + c * 2048 + tid * 8), 16, 0, 0);
    }
  };

  auto RDA = [&](int sl, int r) -> h8 {
    return *(const h8*)(smem + sl * 16384 + (r * 4 + (g ^ ((r >> 1) & 3))) * 8);
  };
  auto RDB = [&](int sl, int r) -> h8 {
    return *(const h8*)(smem + sl * 16384 + 8192 + (r * 4 + (g ^ ((r >> 1) & 3))) * 8);
  };

  f4 acc[8][8] = {};                   // 256 f32 -> AGPRs
  const int NT = K >> 5;

  STAGE(0, 0);
  STAGE(1, 1);
  STAGE(2, 2);
  vmwait<16>();                        // tile 0's 8 loads retired; 1,2 in flight
  __builtin_amdgcn_s_barrier();

  for (int t = 0; t < NT; ++t) {
    const int sl = t & 3;
    h8 af[8], bf[8];
#pragma unroll
    for (int i = 0; i < 8; ++i) af[i] = RDA(sl, wm * 128 + i * 16 + fr);
#pragma unroll
    for (int j = 0; j < 8; ++j) bf[j] = RDB(sl, wn * 128 + j * 16 + fr);
    const int ts = (t + 3 < NT) ? t + 3 : NT - 1;  // tail dups land in freed slots, never read
    STAGE((t + 3) & 3, ts);
    vmwait<16>();                      // tile t+1 landed; t+2 (8) + t+3 (8) in flight
    asm volatile("s_waitcnt lgkmcnt(0)" ::: "memory");
    __builtin_amdgcn_sched_barrier(0);
    __builtin_amdgcn_s_setprio(1);
#pragma unroll
    for (int mi = 0; mi < 8; ++mi)
#pragma unroll
      for (int ni = 0; ni < 8; ++ni)
        acc[mi][ni] = __builtin_amdgcn_mfma_f32_16x16x32_f16(af[mi], bf[ni], acc[mi][ni], 0, 0, 0);
    __builtin_amdgcn_s_setprio(0);
    __builtin_amdgcn_s_barrier();      // slot of t-1 now free for iter t+1's stage
  }
  vmwait<0>();

  // epilogue: U = exp(score*scale + mask) f16 + per-row partial sums
  const int fq = g * 4;
  const float* mk = mask + (long)bz * sC;
  f16* Cp = C + (long)bz * sC;
  float pr[8][4] = {};
#pragma unroll
  for (int mi = 0; mi < 8; ++mi) {
#pragma unroll
    for (int ni = 0; ni < 8; ++ni) {
#pragma unroll
      for (int i = 0; i < 4; ++i) {
        const int row = m0 + wm * 128 + mi * 16 + fq + i;
        const int col = n0 + wn * 128 + ni * 16 + fr;
        const float e = __expf(acc[mi][ni][i] * 0.03125f + mk[(long)row * N + col]);
        Cp[(long)row * N + col] = (f16)e;
        pr[mi][i] += e;
      }
    }
  }
#pragma unroll
  for (int mi = 0; mi < 8; ++mi) {
#pragma unroll
    for (int i = 0; i < 4; ++i) {
      float sv = pr[mi][i];
      sv += __shfl_xor(sv, 1);
      sv += __shfl_xor(sv, 2);
      sv += __shfl_xor(sv, 4);
      sv += __shfl_xor(sv, 8);
      if (fr == 0) {
        const int row = m0 + wm * 128 + mi * 16 + fq + i;
        atomicAdd(&rs[bz * 2048 + row], sv);
      }
    }
  }
}

// ---------- WIDE Big-K GEMM (r15-verbatim, PV only): 128x256, 3-ring, vmcnt(6) ----------
// MODE 6: f32 C = val / rs[bz*2048+row]   (xtra = rowsum)
__global__ __launch_bounds__(256, 2) void gemm128w_pv(const f16* __restrict__ A,
                                                      const f16* __restrict__ Bm,
                                                      void* __restrict__ C,
                                                      const float* __restrict__ xtra,
                                                      int N, int K,
                                                      long sA, long sB, long sC,
                                                      int gx, int gy) {
  __shared__ __align__(16) f16 smem[3 * 12288];  // 72 KiB

  const int cpx = gridDim.x >> 3;
  const int wgid = (blockIdx.x & 7) * cpx + (blockIdx.x >> 3);
  const int by = wgid % gy;
  const int bx = (wgid / gy) % gx;
  const int bz = wgid / (gy * gx);
  A += (long)bz * sA;
  Bm += (long)bz * sB;
  const int m0 = bx * 128, n0 = by * 256;

  const int tid = threadIdx.x;
  const int lane = tid & 63;
  const int w = tid >> 6;
  const int wm = w >> 1, wn = w & 1;
  const int fr = lane & 15;
  const int g = lane >> 4;

  const int r0 = tid >> 2;
  const int s = tid & 3;

  auto STAGE = [&](int sl, int t) {
    const long k0 = (long)t * 32;
#pragma unroll
    for (int c = 0; c < 2; ++c) {
      const int row = c * 64 + r0;
      const int scol = (s ^ ((row >> 1) & 3)) * 8;
      __builtin_amdgcn_global_load_lds(
          (gchar*)(A + (long)(m0 + row) * K + k0 + scol),
          (lchar*)(smem + sl * 12288 + c * 2048 + tid * 8), 16, 0, 0);
    }
#pragma unroll
    for (int c = 0; c < 4; ++c) {
      const int row = c * 64 + r0;
      const int scol = (s ^ ((row >> 1) & 3)) * 8;
      __builtin_amdgcn_global_load_lds(
          (gchar*)(Bm + (long)(n0 + row) * K + k0 + scol),
          (lchar*)(smem + sl * 12288 + 4096 + c * 2048 + tid * 8), 16, 0, 0);
    }
  };

  auto RDA = [&](int sl, int r) -> h8 {
    return *(const h8*)(smem + sl * 12288 + (r * 4 + (g ^ ((r >> 1) & 3))) * 8);
  };
  auto RDB = [&](int sl, int r) -> h8 {
    return *(const h8*)(smem + sl * 12288 + 4096 + (r * 4 + (g ^ ((r >> 1) & 3))) * 8);
  };

  f4 acc[4][8] = {};
  const int NT = K >> 5;

  STAGE(0, 0);
  STAGE(1, 1);
  vmwait<6>();
  __builtin_amdgcn_s_barrier();

  int sl = 0;
  for (int t = 0; t < NT; ++t) {
    h8 af[4], bf[8];
#pragma unroll
    for (int i = 0; i < 4; ++i) af[i] = RDA(sl, wm * 64 + i * 16 + fr);
#pragma unroll
    for (int j = 0; j < 8; ++j) bf[j] = RDB(sl, wn * 128 + j * 16 + fr);
    const int ts = (t + 2 < NT) ? t + 2 : NT - 1;
    int ss = sl + 2; if (ss >= 3) ss -= 3;
    STAGE(ss, ts);
    vmwait<6>();
    asm volatile("s_waitcnt lgkmcnt(0)" ::: "memory");
    __builtin_amdgcn_sched_barrier(0);
    __builtin_amdgcn_s_setprio(1);
#pragma unroll
    for (int mi = 0; mi < 4; ++mi)
#pragma unroll
      for (int ni = 0; ni < 8; ++ni)
        acc[mi][ni] = __builtin_amdgcn_mfma_f32_16x16x32_f16(af[mi], bf[ni], acc[mi][ni], 0, 0, 0);
    __builtin_amdgcn_s_setprio(0);
    __builtin_amdgcn_s_barrier();
    sl = (sl + 1 == 3) ? 0 : sl + 1;
  }
  vmwait<0>();

  const int fq = g * 4;
#pragma unroll
  for (int mi = 0; mi < 4; ++mi) {
#pragma unroll
    for (int i = 0; i < 4; ++i) {
      const int row = m0 + wm * 64 + mi * 16 + fq + i;
      const float inv = 1.0f / xtra[bz * 2048 + row];
      float* Cp = (float*)C + (long)bz * sC;
#pragma unroll
      for (int ni = 0; ni < 8; ++ni) {
        const int col = n0 + wn * 128 + ni * 16 + fr;
        Cp[(long)row * N + col] = acc[mi][ni][i] * inv;
      }
    }
  }
}

extern "C" void kernel_launch(void* const* d_in, const int* in_sizes, int n_in,
                              void* d_out, int out_size, void* d_ws, size_t ws_size,
                              hipStream_t stream) {
  const float* x1 = (const float*)d_in[0];
  const float* x2 = (const float*)d_in[1];
  const float* x3 = (const float*)d_in[2];
  const float* mask = (const float*)d_in[3];
  const float* Wq = (const float*)d_in[4];
  const float* Wk = (const float*)d_in[5];
  const float* Wv = (const float*)d_in[6];

  const long nx = (long)B_ * S_ * D_;
  const long nw = (long)H_ * D_;
  const long nqkv = (long)B_ * S_ * H_;
  const long nsc = (long)B_ * S_ * S_;

  char* ws = (char*)d_ws;
  f16* x1h = (f16*)ws; ws += nx * 2;
  f16* x2h = (f16*)ws; ws += nx * 2;     // scores B-operand
  f16* x3h = (f16*)ws; ws += nx * 2;
  f16* wvh = (f16*)ws; ws += nw * 2;
  f16* wqT = (f16*)ws; ws += nw * 2;
  f16* wkT = (f16*)ws; ws += nw * 2;
  f16* mt  = (f16*)ws; ws += nw * 2;     // Mt[e][d] = sum_h Wk[h][e] Wq[h][d]
  f16* qh  = (f16*)ws; ws += nqkv * 2;   // Qeff = x1 * Mt^T
  f16* vth = (f16*)ws; ws += nqkv * 2;   // V^T [b][h][s]
  f16* sc  = (f16*)ws; ws += nsc * 2;    // U = exp(scores*scale + mask), f16
  float* rowsum = (float*)ws; ws += (long)B_ * S_ * 4;

  hipMemsetAsync(rowsum, 0, (size_t)B_ * S_ * 4, stream);

  const int SMEM_S = 131072;
  hipFuncSetAttribute((const void*)gemm256s, hipFuncAttributeMaxDynamicSharedMemorySize, SMEM_S);

  cast_x<<<dim3(6400), 256, 0, stream>>>(x1, x2, x3, Wv, x1h, x2h, x3h, wvh);
  wtrans<<<dim3(2048), 256, 0, stream>>>(Wq, Wk, wqT, wkT);

  const dim3 blk(256);
  // Mt = WkT * WqT^T : 64 blocks
  gemm_abt<1><<<dim3(8, 8, 1), blk, 0, stream>>>(wkT, wqT, mt, 1024, 1024, 1024, 0, 0, 0);
  // Qeff = x1h * Mt^T
  gemm_abt<1><<<dim3(64, 8, 1), blk, 0, stream>>>(x1h, mt, qh, 8192, 1024, 1024, 0, 0, 0);
  // V^T projection
  gemm_abt<2><<<dim3(64, 8, 1), blk, 0, stream>>>(x3h, wvh, vth, 8192, 1024, 1024, 0, 0, 0);
  // U[b] = exp(Qeff[b] x2[b]^T * scale + mask[b]) -> f16, + rowsum : 8 x 8 x 4 = 256 blocks
  gemm256s<<<dim3(256), blk, SMEM_S, stream>>>(qh, x2h, sc, mask, rowsum, 2048, 1024,
                                               (long)S_ * H_, (long)S_ * D_, (long)S_ * S_, 8, 8);
  // out[b] = (U[b] (V^T[b])^T) / rowsum : 16 x 4 x 4 = 256 blocks
  gemm128w_pv<<<dim3(256), blk, 0, stream>>>(sc, vth, d_out, rowsum, 1024, 2048,
                                             (long)S_ * S_, (long)S_ * H_, (long)S_ * H_, 16, 4);
}

// Round 17
// 205.845 us; speedup vs baseline: 1.3595x; 1.3595x over previous
//
#include <hip/hip_runtime.h>

typedef _Float16 f16;
typedef _Float16 h4 __attribute__((ext_vector_type(4)));
typedef _Float16 h8 __attribute__((ext_vector_type(8)));
typedef float f4 __attribute__((ext_vector_type(4)));

typedef const __attribute__((address_space(1))) char gchar;
typedef __attribute__((address_space(3))) char lchar;

#define B_ 4
#define S_ 2048
#define D_ 1024
#define H_ 1024

template <int N>
__device__ __forceinline__ void vmwait() {
  if constexpr (N == 0) asm volatile("s_waitcnt vmcnt(0)" ::: "memory");
  else if constexpr (N == 6) asm volatile("s_waitcnt vmcnt(6)" ::: "memory");
}

// ---------------- prep: cast x1,x2,x3,Wv (16 elems/thread) + transpose-cast Wq,Wk ----------------
// blocks [0,6400): cast; blocks [6400,8448): 32x32 transpose tiles of Wq/Wk.
__global__ __launch_bounds__(256) void prep(
    const float* __restrict__ x1, const float* __restrict__ x2, const float* __restrict__ x3,
    const float* __restrict__ wv, const float* __restrict__ wq, const float* __restrict__ wk,
    f16* __restrict__ o1, f16* __restrict__ o2, f16* __restrict__ o3, f16* __restrict__ ow,
    f16* __restrict__ oqT, f16* __restrict__ okT) {
  const int bx = blockIdx.x;
  const int tid = threadIdx.x;
  if (bx < 6400) {
    const long g = bx * 256L + tid;
    const float* in;
    f16* out;
    long off;
    if (g < (3L << 19)) {
      const int w = (int)(g >> 19);
      off = (g & ((1L << 19) - 1)) * 16;
      in = w == 0 ? x1 : (w == 1 ? x2 : x3);
      out = w == 0 ? o1 : (w == 1 ? o2 : o3);
    } else {
      off = (g - (3L << 19)) * 16;
      in = wv;
      out = ow;
    }
    float4 a = *(const float4*)(in + off);
    float4 b = *(const float4*)(in + off + 4);
    float4 c = *(const float4*)(in + off + 8);
    float4 d = *(const float4*)(in + off + 12);
    h8 u, v;
    u[0] = (f16)a.x; u[1] = (f16)a.y; u[2] = (f16)a.z; u[3] = (f16)a.w;
    u[4] = (f16)b.x; u[5] = (f16)b.y; u[6] = (f16)b.z; u[7] = (f16)b.w;
    v[0] = (f16)c.x; v[1] = (f16)c.y; v[2] = (f16)c.z; v[3] = (f16)c.w;
    v[4] = (f16)d.x; v[5] = (f16)d.y; v[6] = (f16)d.z; v[7] = (f16)d.w;
    *(h8*)(out + off) = u;
    *(h8*)(out + off + 8) = v;
  } else {
    __shared__ float t[32][33];
    const int bw = bx - 6400;
    const float* in = (bw >> 10) ? wk : wq;
    f16* out = (bw >> 10) ? okT : oqT;
    const int tile = bw & 1023;
    const int tr = tile >> 5, tc = tile & 31;
    {
      const int r = tid >> 3, c4 = (tid & 7) * 4;
      float4 v = *(const float4*)(in + (long)(tr * 32 + r) * 1024 + tc * 32 + c4);
      t[r][c4] = v.x; t[r][c4 + 1] = v.y; t[r][c4 + 2] = v.z; t[r][c4 + 3] = v.w;
    }
    __syncthreads();
    {
      const int rr = tid >> 3, cc4 = (tid & 7) * 4;
      h4 o;
      o[0] = (f16)t[cc4][rr]; o[1] = (f16)t[cc4 + 1][rr];
      o[2] = (f16)t[cc4 + 2][rr]; o[3] = (f16)t[cc4 + 3][rr];
      *(h4*)(out + (long)(tc * 32 + rr) * 1024 + tr * 32 + cc4) = o;
    }
  }
}

// ---------------- small GEMM for Mt: C = A * B^T, 2-slot, syncthreads drain ----------
#define TILE 128
#define BK 32

__global__ __launch_bounds__(256) void gemm_abt1(const f16* __restrict__ A,
                                                 const f16* __restrict__ Bm,
                                                 f16* __restrict__ C,
                                                 int N, int K) {
  __shared__ __align__(16) f16 lA[2][TILE * BK];
  __shared__ __align__(16) f16 lB[2][TILE * BK];

  const int tid = threadIdx.x;
  const int lane = tid & 63;
  const int w = tid >> 6;
  const int wr = w >> 1, wc = w & 1;
  const int m0 = blockIdx.x * TILE;
  const int n0 = blockIdx.y * TILE;

  const int lr = lane >> 2;
  const int lc = (lane & 3) * 8;
  const f16* Abase = A + (long)(m0 + lr) * K + lc;
  const f16* Bbase = Bm + (long)(n0 + lr) * K + lc;

  const int fr = lane & 15;
  const int kg = (lane >> 4) * 8;

  f4 acc[4][4] = {};

  auto STAGE = [&](int buf, int k0) {
#pragma unroll
    for (int c = 0; c < 2; ++c) {
      const int br = w * 32 + c * 16;
      __builtin_amdgcn_global_load_lds(
          (gchar*)(Abase + (long)br * K + k0),
          (lchar*)&lA[buf][br * BK], 16, 0, 0);
      __builtin_amdgcn_global_load_lds(
          (gchar*)(Bbase + (long)br * K + k0),
          (lchar*)&lB[buf][br * BK], 16, 0, 0);
    }
  };

  STAGE(0, 0);
  __syncthreads();

  int cur = 0;
  for (int k0 = 0; k0 < K; k0 += BK) {
    if (k0 + BK < K) STAGE(cur ^ 1, k0 + BK);

    h8 af[4], bf[4];
#pragma unroll
    for (int i = 0; i < 4; ++i) {
      af[i] = *(const h8*)&lA[cur][(wr * 64 + i * 16 + fr) * BK + kg];
      bf[i] = *(const h8*)&lB[cur][(wc * 64 + i * 16 + fr) * BK + kg];
    }
#pragma unroll
    for (int mi = 0; mi < 4; ++mi)
#pragma unroll
      for (int ni = 0; ni < 4; ++ni)
        acc[mi][ni] = __builtin_amdgcn_mfma_f32_16x16x32_f16(af[mi], bf[ni], acc[mi][ni], 0, 0, 0);

    __syncthreads();
    cur ^= 1;
  }

  const int fq = (lane >> 4) * 4;
#pragma unroll
  for (int mi = 0; mi < 4; ++mi)
#pragma unroll
    for (int ni = 0; ni < 4; ++ni)
#pragma unroll
      for (int i = 0; i < 4; ++i) {
        const int row = m0 + wr * 64 + mi * 16 + fq + i;
        const int col = n0 + wc * 64 + ni * 16 + fr;
        C[(long)row * N + col] = (f16)acc[mi][ni][i];
      }
}

// ---------- WIDE GEMM: 128x256 tile, BK=32, 3-ring, counted vmcnt(6), T2 swizzle ----------
// 4 waves as 2x2; per-wave C = 64x128 (4x8 frags) -> 32 MFMA per K-step per wave.
// MODE 1: f16 C[m*N+n] (+bz*sC)                     (Qeff projection)
// MODE 2: f16 V^T scatter C[((row>>11)*N+col)*2048 + (row&2047)]   (V^T projection)
// MODE 5: U = exp(val*scale + mask) -> f16; row partials atomicAdd'ed into rs.
// MODE 6: f32 C = val / xtra[bz*2048+row]           (PV)
template <int MODE>
__global__ __launch_bounds__(256, 2) void gemm128w(const f16* __restrict__ A,
                                                   const f16* __restrict__ Bm,
                                                   void* __restrict__ C,
                                                   const float* __restrict__ xtra,
                                                   float* __restrict__ rs,
                                                   int N, int K,
                                                   long sA, long sB, long sC,
                                                   int gx, int gy) {
  __shared__ __align__(16) f16 smem[3 * 12288];  // 72 KiB

  const int cpx = gridDim.x >> 3;
  const int wgid = (blockIdx.x & 7) * cpx + (blockIdx.x >> 3);
  const int by = wgid % gy;
  const int bx = (wgid / gy) % gx;
  const int bz = wgid / (gy * gx);
  A += (long)bz * sA;
  Bm += (long)bz * sB;
  const int m0 = bx * 128, n0 = by * 256;

  const int tid = threadIdx.x;
  const int lane = tid & 63;
  const int w = tid >> 6;
  const int wm = w >> 1, wn = w & 1;   // 2x2 waves; per-wave 64 rows x 128 cols
  const int fr = lane & 15;
  const int g = lane >> 4;

  const int r0 = tid >> 2;
  const int s = tid & 3;

  auto STAGE = [&](int sl, int t) {
    const long k0 = (long)t * 32;
#pragma unroll
    for (int c = 0; c < 2; ++c) {
      const int row = c * 64 + r0;
      const int scol = (s ^ ((row >> 1) & 3)) * 8;
      __builtin_amdgcn_global_load_lds(
          (gchar*)(A + (long)(m0 + row) * K + k0 + scol),
          (lchar*)(smem + sl * 12288 + c * 2048 + tid * 8), 16, 0, 0);
    }
#pragma unroll
    for (int c = 0; c < 4; ++c) {
      const int row = c * 64 + r0;
      const int scol = (s ^ ((row >> 1) & 3)) * 8;
      __builtin_amdgcn_global_load_lds(
          (gchar*)(Bm + (long)(n0 + row) * K + k0 + scol),
          (lchar*)(smem + sl * 12288 + 4096 + c * 2048 + tid * 8), 16, 0, 0);
    }
  };

  auto RDA = [&](int sl, int r) -> h8 {
    return *(const h8*)(smem + sl * 12288 + (r * 4 + (g ^ ((r >> 1) & 3))) * 8);
  };
  auto RDB = [&](int sl, int r) -> h8 {
    return *(const h8*)(smem + sl * 12288 + 4096 + (r * 4 + (g ^ ((r >> 1) & 3))) * 8);
  };

  f4 acc[4][8] = {};
  const int NT = K >> 5;

  STAGE(0, 0);
  STAGE(1, 1);
  vmwait<6>();
  __builtin_amdgcn_s_barrier();

  int sl = 0;
  for (int t = 0; t < NT; ++t) {
    h8 af[4], bf[8];
#pragma unroll
    for (int i = 0; i < 4; ++i) af[i] = RDA(sl, wm * 64 + i * 16 + fr);
#pragma unroll
    for (int j = 0; j < 8; ++j) bf[j] = RDB(sl, wn * 128 + j * 16 + fr);
    const int ts = (t + 2 < NT) ? t + 2 : NT - 1;
    int ss = sl + 2; if (ss >= 3) ss -= 3;
    STAGE(ss, ts);
    vmwait<6>();                   // tile t+1's 6 loads retired; t+2's in flight
    asm volatile("s_waitcnt lgkmcnt(0)" ::: "memory");
    __builtin_amdgcn_sched_barrier(0);
    __builtin_amdgcn_s_setprio(1);
#pragma unroll
    for (int mi = 0; mi < 4; ++mi)
#pragma unroll
      for (int ni = 0; ni < 8; ++ni)
        acc[mi][ni] = __builtin_amdgcn_mfma_f32_16x16x32_f16(af[mi], bf[ni], acc[mi][ni], 0, 0, 0);
    __builtin_amdgcn_s_setprio(0);
    __builtin_amdgcn_s_barrier();
    sl = (sl + 1 == 3) ? 0 : sl + 1;
  }
  vmwait<0>();

  const int fq = g * 4;
  if constexpr (MODE == 1) {
    f16* Cp = (f16*)C + (long)bz * sC;
#pragma unroll
    for (int mi = 0; mi < 4; ++mi)
#pragma unroll
      for (int ni = 0; ni < 8; ++ni)
#pragma unroll
        for (int i = 0; i < 4; ++i) {
          const int row = m0 + wm * 64 + mi * 16 + fq + i;
          const int col = n0 + wn * 128 + ni * 16 + fr;
          Cp[(long)row * N + col] = (f16)acc[mi][ni][i];
        }
  } else if constexpr (MODE == 2) {
    f16* Cp = (f16*)C;
#pragma unroll
    for (int mi = 0; mi < 4; ++mi)
#pragma unroll
      for (int ni = 0; ni < 8; ++ni)
#pragma unroll
        for (int i = 0; i < 4; ++i) {
          const int row = m0 + wm * 64 + mi * 16 + fq + i;
          const int col = n0 + wn * 128 + ni * 16 + fr;
          const int b = row >> 11, sr = row & 2047;
          Cp[((long)b * N + col) * 2048 + sr] = (f16)acc[mi][ni][i];
        }
  } else if constexpr (MODE == 5) {
    const float* mk = xtra + (long)bz * sC;
    f16* Cp = (f16*)C + (long)bz * sC;
    float pr[4][4] = {};
#pragma unroll
    for (int mi = 0; mi < 4; ++mi) {
#pragma unroll
      for (int ni = 0; ni < 8; ++ni) {
#pragma unroll
        for (int i = 0; i < 4; ++i) {
          const int row = m0 + wm * 64 + mi * 16 + fq + i;
          const int col = n0 + wn * 128 + ni * 16 + fr;
          const float e = __expf(acc[mi][ni][i] * 0.03125f + mk[(long)row * N + col]);
          Cp[(long)row * N + col] = (f16)e;
          pr[mi][i] += e;
        }
      }
    }
#pragma unroll
    for (int mi = 0; mi < 4; ++mi) {
#pragma unroll
      for (int i = 0; i < 4; ++i) {
        float sv = pr[mi][i];
        sv += __shfl_xor(sv, 1);
        sv += __shfl_xor(sv, 2);
        sv += __shfl_xor(sv, 4);
        sv += __shfl_xor(sv, 8);
        if (fr == 0) {
          const int row = m0 + wm * 64 + mi * 16 + fq + i;
          atomicAdd(&rs[bz * 2048 + row], sv);
        }
      }
    }
  } else {
#pragma unroll
    for (int mi = 0; mi < 4; ++mi) {
#pragma unroll
      for (int i = 0; i < 4; ++i) {
        const int row = m0 + wm * 64 + mi * 16 + fq + i;
        const float inv = 1.0f / xtra[bz * 2048 + row];
        float* Cp = (float*)C + (long)bz * sC;
#pragma unroll
        for (int ni = 0; ni < 8; ++ni) {
          const int col = n0 + wn * 128 + ni * 16 + fr;
          Cp[(long)row * N + col] = acc[mi][ni][i] * inv;
        }
      }
    }
  }
}

extern "C" void kernel_launch(void* const* d_in, const int* in_sizes, int n_in,
                              void* d_out, int out_size, void* d_ws, size_t ws_size,
                              hipStream_t stream) {
  const float* x1 = (const float*)d_in[0];
  const float* x2 = (const float*)d_in[1];
  const float* x3 = (const float*)d_in[2];
  const float* mask = (const float*)d_in[3];
  const float* Wq = (const float*)d_in[4];
  const float* Wk = (const float*)d_in[5];
  const float* Wv = (const float*)d_in[6];

  const long nx = (long)B_ * S_ * D_;
  const long nw = (long)H_ * D_;
  const long nqkv = (long)B_ * S_ * H_;
  const long nsc = (long)B_ * S_ * S_;

  char* ws = (char*)d_ws;
  f16* x1h = (f16*)ws; ws += nx * 2;
  f16* x2h = (f16*)ws; ws += nx * 2;     // scores B-operand
  f16* x3h = (f16*)ws; ws += nx * 2;
  f16* wvh = (f16*)ws; ws += nw * 2;
  f16* wqT = (f16*)ws; ws += nw * 2;
  f16* wkT = (f16*)ws; ws += nw * 2;
  f16* mt  = (f16*)ws; ws += nw * 2;     // Mt[e][d] = sum_h Wk[h][e] Wq[h][d]
  f16* qh  = (f16*)ws; ws += nqkv * 2;   // Qeff = x1 * Mt^T
  f16* vth = (f16*)ws; ws += nqkv * 2;   // V^T [b][h][s]
  f16* sc  = (f16*)ws; ws += nsc * 2;    // U = exp(scores*scale + mask), f16
  float* rowsum = (float*)ws; ws += (long)B_ * S_ * 4;

  hipMemsetAsync(rowsum, 0, (size_t)B_ * S_ * 4, stream);

  // prep: casts + weight transposes, one dispatch
  prep<<<dim3(8448), 256, 0, stream>>>(x1, x2, x3, Wv, Wq, Wk,
                                       x1h, x2h, x3h, wvh, wqT, wkT);

  const dim3 blk(256);
  // Mt = WkT * WqT^T : 64 blocks
  gemm_abt1<<<dim3(8, 8), blk, 0, stream>>>(wkT, wqT, mt, 1024, 1024);
  // Qeff = x1h * Mt^T : wide tile, 64 x 4 = 256 blocks
  gemm128w<1><<<dim3(256), blk, 0, stream>>>(x1h, mt, qh, nullptr, nullptr, 1024, 1024,
                                             0, 0, 0, 64, 4);
  // V^T = (x3h * Wv^T)^T : wide tile, 64 x 4 = 256 blocks
  gemm128w<2><<<dim3(256), blk, 0, stream>>>(x3h, wvh, vth, nullptr, nullptr, 1024, 1024,
                                             0, 0, 0, 64, 4);
  // U[b] = exp(Qeff[b] x2[b]^T * scale + mask[b]) -> f16, + rowsum : 16 x 8 x 4 = 512 blocks
  gemm128w<5><<<dim3(512), blk, 0, stream>>>(qh, x2h, sc, mask, rowsum, 2048, 1024,
                                             (long)S_ * H_, (long)S_ * D_, (long)S_ * S_, 16, 8);
  // out[b] = (U[b] (V^T[b])^T) / rowsum : 16 x 4 x 4 = 256 blocks
  gemm128w<6><<<dim3(256), blk, 0, stream>>>(sc, vth, d_out, rowsum, nullptr, 1024, 2048,
                                             (long)S_ * S_, (long)S_ * H_, (long)S_ * H_, 16, 4);
}

// Round 18
// 187.280 us; speedup vs baseline: 1.4943x; 1.0991x over previous
//
#include <hip/hip_runtime.h>

typedef _Float16 f16;
typedef _Float16 h4 __attribute__((ext_vector_type(4)));
typedef _Float16 h8 __attribute__((ext_vector_type(8)));
typedef float f4 __attribute__((ext_vector_type(4)));

typedef const __attribute__((address_space(1))) char gchar;
typedef __attribute__((address_space(3))) char lchar;

#define B_ 4
#define S_ 2048
#define D_ 1024
#define H_ 1024

template <int N>
__device__ __forceinline__ void vmwait() {
  if constexpr (N == 0) asm volatile("s_waitcnt vmcnt(0)" ::: "memory");
  else if constexpr (N == 6) asm volatile("s_waitcnt vmcnt(6)" ::: "memory");
}

// ---------------- prep: cast x1,x2,x3,Wv (16 elems/thread) + transpose-cast Wq,Wk ----------------
__global__ __launch_bounds__(256) void prep(
    const float* __restrict__ x1, const float* __restrict__ x2, const float* __restrict__ x3,
    const float* __restrict__ wv, const float* __restrict__ wq, const float* __restrict__ wk,
    f16* __restrict__ o1, f16* __restrict__ o2, f16* __restrict__ o3, f16* __restrict__ ow,
    f16* __restrict__ oqT, f16* __restrict__ okT) {
  const int bx = blockIdx.x;
  const int tid = threadIdx.x;
  if (bx < 6400) {
    const long g = bx * 256L + tid;
    const float* in;
    f16* out;
    long off;
    if (g < (3L << 19)) {
      const int w = (int)(g >> 19);
      off = (g & ((1L << 19) - 1)) * 16;
      in = w == 0 ? x1 : (w == 1 ? x2 : x3);
      out = w == 0 ? o1 : (w == 1 ? o2 : o3);
    } else {
      off = (g - (3L << 19)) * 16;
      in = wv;
      out = ow;
    }
    float4 a = *(const float4*)(in + off);
    float4 b = *(const float4*)(in + off + 4);
    float4 c = *(const float4*)(in + off + 8);
    float4 d = *(const float4*)(in + off + 12);
    h8 u, v;
    u[0] = (f16)a.x; u[1] = (f16)a.y; u[2] = (f16)a.z; u[3] = (f16)a.w;
    u[4] = (f16)b.x; u[5] = (f16)b.y; u[6] = (f16)b.z; u[7] = (f16)b.w;
    v[0] = (f16)c.x; v[1] = (f16)c.y; v[2] = (f16)c.z; v[3] = (f16)c.w;
    v[4] = (f16)d.x; v[5] = (f16)d.y; v[6] = (f16)d.z; v[7] = (f16)d.w;
    *(h8*)(out + off) = u;
    *(h8*)(out + off + 8) = v;
  } else {
    __shared__ float t[32][33];
    const int bw = bx - 6400;
    const float* in = (bw >> 10) ? wk : wq;
    f16* out = (bw >> 10) ? okT : oqT;
    const int tile = bw & 1023;
    const int tr = tile >> 5, tc = tile & 31;
    {
      const int r = tid >> 3, c4 = (tid & 7) * 4;
      float4 v = *(const float4*)(in + (long)(tr * 32 + r) * 1024 + tc * 32 + c4);
      t[r][c4] = v.x; t[r][c4 + 1] = v.y; t[r][c4 + 2] = v.z; t[r][c4 + 3] = v.w;
    }
    __syncthreads();
    {
      const int rr = tid >> 3, cc4 = (tid & 7) * 4;
      h4 o;
      o[0] = (f16)t[cc4][rr]; o[1] = (f16)t[cc4 + 1][rr];
      o[2] = (f16)t[cc4 + 2][rr]; o[3] = (f16)t[cc4 + 3][rr];
      *(h4*)(out + (long)(tc * 32 + rr) * 1024 + tr * 32 + cc4) = o;
    }
  }
}

#define TILE 128
#define BK 32

// ---------- union dispatch: blocks [0,256) V^T projection (wide tile); [256,320) Mt ----------
// V^T: A=x3h [8192x1024], B=wvh [1024x1024]; C[((row>>11)*1024+col)*2048 + (row&2047)] f16.
// Mt : A=wkT, B=wqT [1024x1024]; C[row*1024+col] f16.
__global__ __launch_bounds__(256, 2) void vt_mt(const f16* __restrict__ x3h,
                                                const f16* __restrict__ wvh,
                                                f16* __restrict__ vth,
                                                const f16* __restrict__ wkT,
                                                const f16* __restrict__ wqT,
                                                f16* __restrict__ mt) {
  __shared__ __align__(16) f16 smem[3 * 12288];  // 72 KiB (V^T branch); Mt uses 32 KiB of it

  const int tid = threadIdx.x;
  const int lane = tid & 63;
  const int w = tid >> 6;
  const int fr = lane & 15;
  const int g = lane >> 4;

  if (blockIdx.x < 256) {
    // ---- V^T: 128x256 tile, 3-ring, counted vmcnt(6), involution swizzle ----
    const int bx0 = blockIdx.x;
    const int wgid = (bx0 & 7) * 32 + (bx0 >> 3);  // bijective over 256
    const int by = wgid & 3;            // gy = 4
    const int bx = wgid >> 2;           // gx = 64
    const int m0 = bx * 128, n0 = by * 256;
    const int K = 1024, N = 1024;

    const int wm = w >> 1, wn = w & 1;
    const int r0 = tid >> 2;
    const int s = tid & 3;

    auto STAGE = [&](int sl, int t) {
      const long k0 = (long)t * 32;
#pragma unroll
      for (int c = 0; c < 2; ++c) {
        const int row = c * 64 + r0;
        const int scol = (s ^ ((row >> 1) & 3)) * 8;
        __builtin_amdgcn_global_load_lds(
            (gchar*)(x3h + (long)(m0 + row) * K + k0 + scol),
            (lchar*)(smem + sl * 12288 + c * 2048 + tid * 8), 16, 0, 0);
      }
#pragma unroll
      for (int c = 0; c < 4; ++c) {
        const int row = c * 64 + r0;
        const int scol = (s ^ ((row >> 1) & 3)) * 8;
        __builtin_amdgcn_global_load_lds(
            (gchar*)(wvh + (long)(n0 + row) * K + k0 + scol),
            (lchar*)(smem + sl * 12288 + 4096 + c * 2048 + tid * 8), 16, 0, 0);
      }
    };
    auto RDA = [&](int sl, int r) -> h8 {
      return *(const h8*)(smem + sl * 12288 + (r * 4 + (g ^ ((r >> 1) & 3))) * 8);
    };
    auto RDB = [&](int sl, int r) -> h8 {
      return *(const h8*)(smem + sl * 12288 + 4096 + (r * 4 + (g ^ ((r >> 1) & 3))) * 8);
    };

    f4 acc[4][8] = {};
    const int NT = K >> 5;

    STAGE(0, 0);
    STAGE(1, 1);
    vmwait<6>();
    __builtin_amdgcn_s_barrier();

    int sl = 0;
    for (int t = 0; t < NT; ++t) {
      h8 af[4], bf[8];
#pragma unroll
      for (int i = 0; i < 4; ++i) af[i] = RDA(sl, wm * 64 + i * 16 + fr);
#pragma unroll
      for (int j = 0; j < 8; ++j) bf[j] = RDB(sl, wn * 128 + j * 16 + fr);
      const int ts = (t + 2 < NT) ? t + 2 : NT - 1;
      int ss = sl + 2; if (ss >= 3) ss -= 3;
      STAGE(ss, ts);
      vmwait<6>();
      asm volatile("s_waitcnt lgkmcnt(0)" ::: "memory");
      __builtin_amdgcn_sched_barrier(0);
      __builtin_amdgcn_s_setprio(1);
#pragma unroll
      for (int mi = 0; mi < 4; ++mi)
#pragma unroll
        for (int ni = 0; ni < 8; ++ni)
          acc[mi][ni] = __builtin_amdgcn_mfma_f32_16x16x32_f16(af[mi], bf[ni], acc[mi][ni], 0, 0, 0);
      __builtin_amdgcn_s_setprio(0);
      __builtin_amdgcn_s_barrier();
      sl = (sl + 1 == 3) ? 0 : sl + 1;
    }
    vmwait<0>();

    const int fq = g * 4;
#pragma unroll
    for (int mi = 0; mi < 4; ++mi)
#pragma unroll
      for (int ni = 0; ni < 8; ++ni)
#pragma unroll
        for (int i = 0; i < 4; ++i) {
          const int row = m0 + w / 2 * 64 + mi * 16 + fq + i;
          const int col = n0 + (w & 1) * 128 + ni * 16 + fr;
          const int b = row >> 11, sr = row & 2047;
          vth[((long)b * N + col) * 2048 + sr] = (f16)acc[mi][ni][i];
        }
  } else {
    // ---- Mt: 128x128 tile, 2-slot syncthreads loop (r3 structure) ----
    const int bx2 = blockIdx.x - 256;   // 0..63
    const int m0 = (bx2 >> 3) * TILE;
    const int n0 = (bx2 & 7) * TILE;
    const int K = 1024, N = 1024;
    const int wr = w >> 1, wc = w & 1;

    const int lr = lane >> 2;
    const int lc = (lane & 3) * 8;
    const f16* Abase = wkT + (long)(m0 + lr) * K + lc;
    const f16* Bbase = wqT + (long)(n0 + lr) * K + lc;
    const int kg = g * 8;

    f4 acc[4][4] = {};

    auto STAGE2 = [&](int buf, int k0) {
#pragma unroll
      for (int c = 0; c < 2; ++c) {
        const int br = w * 32 + c * 16;
        __builtin_amdgcn_global_load_lds(
            (gchar*)(Abase + (long)br * K + k0),
            (lchar*)(smem + buf * 4096 + br * BK), 16, 0, 0);
        __builtin_amdgcn_global_load_lds(
            (gchar*)(Bbase + (long)br * K + k0),
            (lchar*)(smem + 8192 + buf * 4096 + br * BK), 16, 0, 0);
      }
    };

    STAGE2(0, 0);
    __syncthreads();

    int cur = 0;
    for (int k0 = 0; k0 < K; k0 += BK) {
      if (k0 + BK < K) STAGE2(cur ^ 1, k0 + BK);
      h8 af[4], bf[4];
#pragma unroll
      for (int i = 0; i < 4; ++i) {
        af[i] = *(const h8*)(smem + cur * 4096 + (wr * 64 + i * 16 + fr) * BK + kg);
        bf[i] = *(const h8*)(smem + 8192 + cur * 4096 + (wc * 64 + i * 16 + fr) * BK + kg);
      }
#pragma unroll
      for (int mi = 0; mi < 4; ++mi)
#pragma unroll
        for (int ni = 0; ni < 4; ++ni)
          acc[mi][ni] = __builtin_amdgcn_mfma_f32_16x16x32_f16(af[mi], bf[ni], acc[mi][ni], 0, 0, 0);
      __syncthreads();
      cur ^= 1;
    }

    const int fq = g * 4;
#pragma unroll
    for (int mi = 0; mi < 4; ++mi)
#pragma unroll
      for (int ni = 0; ni < 4; ++ni)
#pragma unroll
        for (int i = 0; i < 4; ++i) {
          const int row = m0 + wr * 64 + mi * 16 + fq + i;
          const int col = n0 + wc * 64 + ni * 16 + fr;
          mt[(long)row * N + col] = (f16)acc[mi][ni][i];
        }
  }
}

// ---------- WIDE GEMM: 128x256 tile, BK=32, 3-ring, counted vmcnt(6), T2 swizzle ----------
// MODE 1: f16 C[m*N+n]                       (Qeff projection)
// MODE 5: U = exp(val*scale + mask) -> f16   (scores; xtra = mask f32, per-batch stride sC)
// MODE 6: f32 C = val / rowsum               (PV; rowsum computed in-kernel from A=U)
template <int MODE>
__global__ __launch_bounds__(256, 2) void gemm128w(const f16* __restrict__ A,
                                                   const f16* __restrict__ Bm,
                                                   void* __restrict__ C,
                                                   const float* __restrict__ xtra,
                                                   int N, int K,
                                                   long sA, long sB, long sC,
                                                   int gx, int gy) {
  __shared__ __align__(16) f16 smem[3 * 12288];  // 72 KiB

  const int cpx = gridDim.x >> 3;
  const int wgid = (blockIdx.x & 7) * cpx + (blockIdx.x >> 3);
  const int by = wgid % gy;
  const int bx = (wgid / gy) % gx;
  const int bz = wgid / (gy * gx);
  A += (long)bz * sA;
  Bm += (long)bz * sB;
  const int m0 = bx * 128, n0 = by * 256;

  const int tid = threadIdx.x;
  const int lane = tid & 63;
  const int w = tid >> 6;
  const int wm = w >> 1, wn = w & 1;   // 2x2 waves; per-wave 64 rows x 128 cols
  const int fr = lane & 15;
  const int g = lane >> 4;

  const int r0 = tid >> 2;
  const int s = tid & 3;

  auto STAGE = [&](int sl, int t) {
    const long k0 = (long)t * 32;
#pragma unroll
    for (int c = 0; c < 2; ++c) {
      const int row = c * 64 + r0;
      const int scol = (s ^ ((row >> 1) & 3)) * 8;
      __builtin_amdgcn_global_load_lds(
          (gchar*)(A + (long)(m0 + row) * K + k0 + scol),
          (lchar*)(smem + sl * 12288 + c * 2048 + tid * 8), 16, 0, 0);
    }
#pragma unroll
    for (int c = 0; c < 4; ++c) {
      const int row = c * 64 + r0;
      const int scol = (s ^ ((row >> 1) & 3)) * 8;
      __builtin_amdgcn_global_load_lds(
          (gchar*)(Bm + (long)(n0 + row) * K + k0 + scol),
          (lchar*)(smem + sl * 12288 + 4096 + c * 2048 + tid * 8), 16, 0, 0);
    }
  };

  auto RDA = [&](int sl, int r) -> h8 {
    return *(const h8*)(smem + sl * 12288 + (r * 4 + (g ^ ((r >> 1) & 3))) * 8);
  };
  auto RDB = [&](int sl, int r) -> h8 {
    return *(const h8*)(smem + sl * 12288 + 4096 + (r * 4 + (g ^ ((r >> 1) & 3))) * 8);
  };

  f4 acc[4][8] = {};
  float pr[4] = {0.f, 0.f, 0.f, 0.f};  // MODE 6: per-A-frag-row partial sums of U
  const int NT = K >> 5;

  STAGE(0, 0);
  STAGE(1, 1);
  vmwait<6>();
  __builtin_amdgcn_s_barrier();

  int sl = 0;
  for (int t = 0; t < NT; ++t) {
    h8 af[4], bf[8];
#pragma unroll
    for (int i = 0; i < 4; ++i) af[i] = RDA(sl, wm * 64 + i * 16 + fr);
#pragma unroll
    for (int j = 0; j < 8; ++j) bf[j] = RDB(sl, wn * 128 + j * 16 + fr);
    if constexpr (MODE == 6) {
      // rowsum accumulation: f16 tree-sum of each af (8 vals), f32 accumulate.
#pragma unroll
      for (int i = 0; i < 4; ++i) {
        f16 t0 = (f16)(((af[i][0] + af[i][1]) + (af[i][2] + af[i][3])) +
                       ((af[i][4] + af[i][5]) + (af[i][6] + af[i][7])));
        pr[i] += (float)t0;
      }
    }
    const int ts = (t + 2 < NT) ? t + 2 : NT - 1;
    int ss = sl + 2; if (ss >= 3) ss -= 3;
    STAGE(ss, ts);
    vmwait<6>();                   // tile t+1's 6 loads retired; t+2's in flight
    asm volatile("s_waitcnt lgkmcnt(0)" ::: "memory");
    __builtin_amdgcn_sched_barrier(0);
    __builtin_amdgcn_s_setprio(1);
#pragma unroll
    for (int mi = 0; mi < 4; ++mi)
#pragma unroll
      for (int ni = 0; ni < 8; ++ni)
        acc[mi][ni] = __builtin_amdgcn_mfma_f32_16x16x32_f16(af[mi], bf[ni], acc[mi][ni], 0, 0, 0);
    __builtin_amdgcn_s_setprio(0);
    __builtin_amdgcn_s_barrier();
    sl = (sl + 1 == 3) ? 0 : sl + 1;
  }
  vmwait<0>();

  const int fq = g * 4;
  if constexpr (MODE == 1) {
    f16* Cp = (f16*)C;
#pragma unroll
    for (int mi = 0; mi < 4; ++mi)
#pragma unroll
      for (int ni = 0; ni < 8; ++ni)
#pragma unroll
        for (int i = 0; i < 4; ++i) {
          const int row = m0 + wm * 64 + mi * 16 + fq + i;
          const int col = n0 + wn * 128 + ni * 16 + fr;
          Cp[(long)row * N + col] = (f16)acc[mi][ni][i];
        }
  } else if constexpr (MODE == 5) {
    const float* mk = xtra + (long)bz * sC;
    f16* Cp = (f16*)C + (long)bz * sC;
#pragma unroll
    for (int mi = 0; mi < 4; ++mi)
#pragma unroll
      for (int ni = 0; ni < 8; ++ni)
#pragma unroll
        for (int i = 0; i < 4; ++i) {
          const int row = m0 + wm * 64 + mi * 16 + fq + i;
          const int col = n0 + wn * 128 + ni * 16 + fr;
          Cp[(long)row * N + col] =
              (f16)__expf(acc[mi][ni][i] * 0.03125f + mk[(long)row * N + col]);
        }
  } else {
    // MODE 6: finish rowsums and divide.
    // pr[mi] holds this thread's k-partial for A-row (wm*64 + mi*16 + fr); lanes with the
    // same fr across g hold disjoint k-slices -> reduce over g (xor 16, 32). Then output
    // row indices are fq+i in the fr-slot, so gather from lane (fq+i).
    float* Cp = (float*)C + (long)bz * sC;
#pragma unroll
    for (int mi = 0; mi < 4; ++mi) {
      float sv = pr[mi];
      sv += __shfl_xor(sv, 16);
      sv += __shfl_xor(sv, 32);   // sv = full rowsum for row (.. + mi*16 + fr), all g agree
#pragma unroll
      for (int i = 0; i < 4; ++i) {
        const float rsv = __shfl(sv, fq + i);   // rowsum for row (.. + mi*16 + fq + i)
        const float inv = 1.0f / rsv;
        const int row = m0 + wm * 64 + mi * 16 + fq + i;
#pragma unroll
        for (int ni = 0; ni < 8; ++ni) {
          const int col = n0 + wn * 128 + ni * 16 + fr;
          Cp[(long)row * N + col] = acc[mi][ni][i] * inv;
        }
      }
    }
  }
}

extern "C" void kernel_launch(void* const* d_in, const int* in_sizes, int n_in,
                              void* d_out, int out_size, void* d_ws, size_t ws_size,
                              hipStream_t stream) {
  const float* x1 = (const float*)d_in[0];
  const float* x2 = (const float*)d_in[1];
  const float* x3 = (const float*)d_in[2];
  const float* mask = (const float*)d_in[3];
  const float* Wq = (const float*)d_in[4];
  const float* Wk = (const float*)d_in[5];
  const float* Wv = (const float*)d_in[6];

  const long nx = (long)B_ * S_ * D_;
  const long nw = (long)H_ * D_;
  const long nqkv = (long)B_ * S_ * H_;
  const long nsc = (long)B_ * S_ * S_;

  char* ws = (char*)d_ws;
  f16* x1h = (f16*)ws; ws += nx * 2;
  f16* x2h = (f16*)ws; ws += nx * 2;     // scores B-operand
  f16* x3h = (f16*)ws; ws += nx * 2;
  f16* wvh = (f16*)ws; ws += nw * 2;
  f16* wqT = (f16*)ws; ws += nw * 2;
  f16* wkT = (f16*)ws; ws += nw * 2;
  f16* mt  = (f16*)ws; ws += nw * 2;     // Mt[e][d] = sum_h Wk[h][e] Wq[h][d]
  f16* qh  = (f16*)ws; ws += nqkv * 2;   // Qeff = x1 * Mt^T
  f16* vth = (f16*)ws; ws += nqkv * 2;   // V^T [b][h][s]
  f16* sc  = (f16*)ws; ws += nsc * 2;    // U = exp(scores*scale + mask), f16

  // prep: casts + weight transposes, one dispatch
  prep<<<dim3(8448), 256, 0, stream>>>(x1, x2, x3, Wv, Wq, Wk,
                                       x1h, x2h, x3h, wvh, wqT, wkT);

  const dim3 blk(256);
  // union: V^T projection (256 blocks) + Mt (64 blocks)
  vt_mt<<<dim3(320), blk, 0, stream>>>(x3h, wvh, vth, wkT, wqT, mt);
  // Qeff = x1h * Mt^T : wide tile, 64 x 4 = 256 blocks
  gemm128w<1><<<dim3(256), blk, 0, stream>>>(x1h, mt, qh, nullptr, 1024, 1024,
                                             0, 0, 0, 64, 4);
  // U[b] = exp(Qeff[b] x2[b]^T * scale + mask[b]) -> f16 : 16 x 8 x 4 = 512 blocks
  gemm128w<5><<<dim3(512), blk, 0, stream>>>(qh, x2h, sc, mask, 2048, 1024,
                                             (long)S_ * H_, (long)S_ * D_, (long)S_ * S_, 16, 8);
  // out[b] = (U[b] (V^T[b])^T) / rowsum(U)  : 16 x 4 x 4 = 256 blocks, rowsum in-kernel
  gemm128w<6><<<dim3(256), blk, 0, stream>>>(sc, vth, d_out, nullptr, 1024, 2048,
                                             (long)S_ * S_, (long)S_ * H_, (long)S_ * H_, 16, 4);
}

// Round 19
// 186.081 us; speedup vs baseline: 1.5039x; 1.0064x over previous
//
#include <hip/hip_runtime.h>

typedef _Float16 f16;
typedef _Float16 h4 __attribute__((ext_vector_type(4)));
typedef _Float16 h8 __attribute__((ext_vector_type(8)));
typedef float f4 __attribute__((ext_vector_type(4)));

typedef const __attribute__((address_space(1))) char gchar;
typedef __attribute__((address_space(3))) char lchar;

#define B_ 4
#define S_ 2048
#define D_ 1024
#define H_ 1024

template <int N>
__device__ __forceinline__ void vmwait() {
  if constexpr (N == 0) asm volatile("s_waitcnt vmcnt(0)" ::: "memory");
  else if constexpr (N == 6) asm volatile("s_waitcnt vmcnt(6)" ::: "memory");
}

// ---------------- prep: cast x1,x2,x3,Wv (16 elems/thread) + transpose-cast Wq,Wk ----------------
__global__ __launch_bounds__(256) void prep(
    const float* __restrict__ x1, const float* __restrict__ x2, const float* __restrict__ x3,
    const float* __restrict__ wv, const float* __restrict__ wq, const float* __restrict__ wk,
    f16* __restrict__ o1, f16* __restrict__ o2, f16* __restrict__ o3, f16* __restrict__ ow,
    f16* __restrict__ oqT, f16* __restrict__ okT) {
  const int bx = blockIdx.x;
  const int tid = threadIdx.x;
  if (bx < 6400) {
    const long g = bx * 256L + tid;
    const float* in;
    f16* out;
    long off;
    if (g < (3L << 19)) {
      const int w = (int)(g >> 19);
      off = (g & ((1L << 19) - 1)) * 16;
      in = w == 0 ? x1 : (w == 1 ? x2 : x3);
      out = w == 0 ? o1 : (w == 1 ? o2 : o3);
    } else {
      off = (g - (3L << 19)) * 16;
      in = wv;
      out = ow;
    }
    float4 a = *(const float4*)(in + off);
    float4 b = *(const float4*)(in + off + 4);
    float4 c = *(const float4*)(in + off + 8);
    float4 d = *(const float4*)(in + off + 12);
    h8 u, v;
    u[0] = (f16)a.x; u[1] = (f16)a.y; u[2] = (f16)a.z; u[3] = (f16)a.w;
    u[4] = (f16)b.x; u[5] = (f16)b.y; u[6] = (f16)b.z; u[7] = (f16)b.w;
    v[0] = (f16)c.x; v[1] = (f16)c.y; v[2] = (f16)c.z; v[3] = (f16)c.w;
    v[4] = (f16)d.x; v[5] = (f16)d.y; v[6] = (f16)d.z; v[7] = (f16)d.w;
    *(h8*)(out + off) = u;
    *(h8*)(out + off + 8) = v;
  } else {
    __shared__ float t[32][33];
    const int bw = bx - 6400;
    const float* in = (bw >> 10) ? wk : wq;
    f16* out = (bw >> 10) ? okT : oqT;
    const int tile = bw & 1023;
    const int tr = tile >> 5, tc = tile & 31;
    {
      const int r = tid >> 3, c4 = (tid & 7) * 4;
      float4 v = *(const float4*)(in + (long)(tr * 32 + r) * 1024 + tc * 32 + c4);
      t[r][c4] = v.x; t[r][c4 + 1] = v.y; t[r][c4 + 2] = v.z; t[r][c4 + 3] = v.w;
    }
    __syncthreads();
    {
      const int rr = tid >> 3, cc4 = (tid & 7) * 4;
      h4 o;
      o[0] = (f16)t[cc4][rr]; o[1] = (f16)t[cc4 + 1][rr];
      o[2] = (f16)t[cc4 + 2][rr]; o[3] = (f16)t[cc4 + 3][rr];
      *(h4*)(out + (long)(tc * 32 + rr) * 1024 + tr * 32 + cc4) = o;
    }
  }
}

#define TILE 128
#define BK 32

// ---------- union dispatch: blocks [0,256) V^T projection (wide tile); [256,320) Mt ----------
__global__ __launch_bounds__(256, 2) void vt_mt(const f16* __restrict__ x3h,
                                                const f16* __restrict__ wvh,
                                                f16* __restrict__ vth,
                                                const f16* __restrict__ wkT,
                                                const f16* __restrict__ wqT,
                                                f16* __restrict__ mt) {
  __shared__ __align__(16) f16 smem[3 * 12288];  // 72 KiB (V^T branch); Mt uses 32 KiB

  const int tid = threadIdx.x;
  const int lane = tid & 63;
  const int w = tid >> 6;
  const int fr = lane & 15;
  const int g = lane >> 4;

  if (blockIdx.x < 256) {
    const int bx0 = blockIdx.x;
    const int wgid = (bx0 & 7) * 32 + (bx0 >> 3);  // bijective over 256
    const int by = wgid & 3;            // gy = 4
    const int bx = wgid >> 2;           // gx = 64
    const int m0 = bx * 128, n0 = by * 256;
    const int K = 1024, N = 1024;

    const int wm = w >> 1, wn = w & 1;
    const int r0 = tid >> 2;
    const int s = tid & 3;

    auto STAGE = [&](int sl, int t) {
      const long k0 = (long)t * 32;
#pragma unroll
      for (int c = 0; c < 2; ++c) {
        const int row = c * 64 + r0;
        const int scol = (s ^ ((row >> 1) & 3)) * 8;
        __builtin_amdgcn_global_load_lds(
            (gchar*)(x3h + (long)(m0 + row) * K + k0 + scol),
            (lchar*)(smem + sl * 12288 + c * 2048 + tid * 8), 16, 0, 0);
      }
#pragma unroll
      for (int c = 0; c < 4; ++c) {
        const int row = c * 64 + r0;
        const int scol = (s ^ ((row >> 1) & 3)) * 8;
        __builtin_amdgcn_global_load_lds(
            (gchar*)(wvh + (long)(n0 + row) * K + k0 + scol),
            (lchar*)(smem + sl * 12288 + 4096 + c * 2048 + tid * 8), 16, 0, 0);
      }
    };
    auto RDA = [&](int sl, int r) -> h8 {
      return *(const h8*)(smem + sl * 12288 + (r * 4 + (g ^ ((r >> 1) & 3))) * 8);
    };
    auto RDB = [&](int sl, int r) -> h8 {
      return *(const h8*)(smem + sl * 12288 + 4096 + (r * 4 + (g ^ ((r >> 1) & 3))) * 8);
    };

    f4 acc[4][8] = {};
    const int NT = K >> 5;

    STAGE(0, 0);
    STAGE(1, 1);
    vmwait<6>();
    __builtin_amdgcn_s_barrier();

    int sl = 0;
    for (int t = 0; t < NT; ++t) {
      h8 af[4], bf[8];
#pragma unroll
      for (int i = 0; i < 4; ++i) af[i] = RDA(sl, wm * 64 + i * 16 + fr);
#pragma unroll
      for (int j = 0; j < 8; ++j) bf[j] = RDB(sl, wn * 128 + j * 16 + fr);
      const int ts = (t + 2 < NT) ? t + 2 : NT - 1;
      int ss = sl + 2; if (ss >= 3) ss -= 3;
      STAGE(ss, ts);
      vmwait<6>();
      asm volatile("s_waitcnt lgkmcnt(0)" ::: "memory");
      __builtin_amdgcn_sched_barrier(0);
      __builtin_amdgcn_s_setprio(1);
#pragma unroll
      for (int mi = 0; mi < 4; ++mi)
#pragma unroll
        for (int ni = 0; ni < 8; ++ni)
          acc[mi][ni] = __builtin_amdgcn_mfma_f32_16x16x32_f16(af[mi], bf[ni], acc[mi][ni], 0, 0, 0);
      __builtin_amdgcn_s_setprio(0);
      __builtin_amdgcn_s_barrier();
      sl = (sl + 1 == 3) ? 0 : sl + 1;
    }
    vmwait<0>();

    const int fq = g * 4;
#pragma unroll
    for (int mi = 0; mi < 4; ++mi)
#pragma unroll
      for (int ni = 0; ni < 8; ++ni)
#pragma unroll
        for (int i = 0; i < 4; ++i) {
          const int row = m0 + wm * 64 + mi * 16 + fq + i;
          const int col = n0 + wn * 128 + ni * 16 + fr;
          const int b = row >> 11, sr = row & 2047;
          vth[((long)b * N + col) * 2048 + sr] = (f16)acc[mi][ni][i];
        }
  } else {
    // ---- Mt: 128x128 tile, 2-slot syncthreads loop ----
    const int bx2 = blockIdx.x - 256;
    const int m0 = (bx2 >> 3) * TILE;
    const int n0 = (bx2 & 7) * TILE;
    const int K = 1024, N = 1024;
    const int wr = w >> 1, wc = w & 1;

    const int lr = lane >> 2;
    const int lc = (lane & 3) * 8;
    const f16* Abase = wkT + (long)(m0 + lr) * K + lc;
    const f16* Bbase = wqT + (long)(n0 + lr) * K + lc;
    const int kg = g * 8;

    f4 acc[4][4] = {};

    auto STAGE2 = [&](int buf, int k0) {
#pragma unroll
      for (int c = 0; c < 2; ++c) {
        const int br = w * 32 + c * 16;
        __builtin_amdgcn_global_load_lds(
            (gchar*)(Abase + (long)br * K + k0),
            (lchar*)(smem + buf * 4096 + br * BK), 16, 0, 0);
        __builtin_amdgcn_global_load_lds(
            (gchar*)(Bbase + (long)br * K + k0),
            (lchar*)(smem + 8192 + buf * 4096 + br * BK), 16, 0, 0);
      }
    };

    STAGE2(0, 0);
    __syncthreads();

    int cur = 0;
    for (int k0 = 0; k0 < K; k0 += BK) {
      if (k0 + BK < K) STAGE2(cur ^ 1, k0 + BK);
      h8 af[4], bf[4];
#pragma unroll
      for (int i = 0; i < 4; ++i) {
        af[i] = *(const h8*)(smem + cur * 4096 + (wr * 64 + i * 16 + fr) * BK + kg);
        bf[i] = *(const h8*)(smem + 8192 + cur * 4096 + (wc * 64 + i * 16 + fr) * BK + kg);
      }
#pragma unroll
      for (int mi = 0; mi < 4; ++mi)
#pragma unroll
        for (int ni = 0; ni < 4; ++ni)
          acc[mi][ni] = __builtin_amdgcn_mfma_f32_16x16x32_f16(af[mi], bf[ni], acc[mi][ni], 0, 0, 0);
      __syncthreads();
      cur ^= 1;
    }

    const int fq = g * 4;
#pragma unroll
    for (int mi = 0; mi < 4; ++mi)
#pragma unroll
      for (int ni = 0; ni < 4; ++ni)
#pragma unroll
        for (int i = 0; i < 4; ++i) {
          const int row = m0 + wr * 64 + mi * 16 + fq + i;
          const int col = n0 + wc * 64 + ni * 16 + fr;
          mt[(long)row * N + col] = (f16)acc[mi][ni][i];
        }
  }
}

// ---------- WIDE GEMM: 128x256 tile, BK=32, 3-ring, counted vmcnt(6), T2 swizzle ----------
// MODE 1: f16 C = val * 0.03125 (Qeff projection, pre-scaled for scores)
// MODE 5: U = exp(val + mask) -> f16 (scores; mask loads double-buffered over mi-blocks)
// MODE 6: f32 C = val / rowsum (PV; rowsum computed in-kernel from A=U)
template <int MODE>
__global__ __launch_bounds__(256, 2) void gemm128w(const f16* __restrict__ A,
                                                   const f16* __restrict__ Bm,
                                                   void* __restrict__ C,
                                                   const float* __restrict__ xtra,
                                                   int N, int K,
                                                   long sA, long sB, long sC,
                                                   int gx, int gy) {
  __shared__ __align__(16) f16 smem[3 * 12288];  // 72 KiB

  const int cpx = gridDim.x >> 3;
  const int wgid = (blockIdx.x & 7) * cpx + (blockIdx.x >> 3);
  const int by = wgid % gy;
  const int bx = (wgid / gy) % gx;
  const int bz = wgid / (gy * gx);
  A += (long)bz * sA;
  Bm += (long)bz * sB;
  const int m0 = bx * 128, n0 = by * 256;

  const int tid = threadIdx.x;
  const int lane = tid & 63;
  const int w = tid >> 6;
  const int wm = w >> 1, wn = w & 1;   // 2x2 waves; per-wave 64 rows x 128 cols
  const int fr = lane & 15;
  const int g = lane >> 4;

  const int r0 = tid >> 2;
  const int s = tid & 3;

  auto STAGE = [&](int sl, int t) {
    const long k0 = (long)t * 32;
#pragma unroll
    for (int c = 0; c < 2; ++c) {
      const int row = c * 64 + r0;
      const int scol = (s ^ ((row >> 1) & 3)) * 8;
      __builtin_amdgcn_global_load_lds(
          (gchar*)(A + (long)(m0 + row) * K + k0 + scol),
          (lchar*)(smem + sl * 12288 + c * 2048 + tid * 8), 16, 0, 0);
    }
#pragma unroll
    for (int c = 0; c < 4; ++c) {
      const int row = c * 64 + r0;
      const int scol = (s ^ ((row >> 1) & 3)) * 8;
      __builtin_amdgcn_global_load_lds(
          (gchar*)(Bm + (long)(n0 + row) * K + k0 + scol),
          (lchar*)(smem + sl * 12288 + 4096 + c * 2048 + tid * 8), 16, 0, 0);
    }
  };

  auto RDA = [&](int sl, int r) -> h8 {
    return *(const h8*)(smem + sl * 12288 + (r * 4 + (g ^ ((r >> 1) & 3))) * 8);
  };
  auto RDB = [&](int sl, int r) -> h8 {
    return *(const h8*)(smem + sl * 12288 + 4096 + (r * 4 + (g ^ ((r >> 1) & 3))) * 8);
  };

  f4 acc[4][8] = {};
  float pr[4] = {0.f, 0.f, 0.f, 0.f};  // MODE 6: per-A-frag-row partial sums of U
  const int NT = K >> 5;

  STAGE(0, 0);
  STAGE(1, 1);
  vmwait<6>();
  __builtin_amdgcn_s_barrier();

  int sl = 0;
  for (int t = 0; t < NT; ++t) {
    h8 af[4], bf[8];
#pragma unroll
    for (int i = 0; i < 4; ++i) af[i] = RDA(sl, wm * 64 + i * 16 + fr);
#pragma unroll
    for (int j = 0; j < 8; ++j) bf[j] = RDB(sl, wn * 128 + j * 16 + fr);
    if constexpr (MODE == 6) {
#pragma unroll
      for (int i = 0; i < 4; ++i) {
        f16 t0 = (f16)(((af[i][0] + af[i][1]) + (af[i][2] + af[i][3])) +
                       ((af[i][4] + af[i][5]) + (af[i][6] + af[i][7])));
        pr[i] += (float)t0;
      }
    }
    const int ts = (t + 2 < NT) ? t + 2 : NT - 1;
    int ss = sl + 2; if (ss >= 3) ss -= 3;
    STAGE(ss, ts);
    vmwait<6>();                   // tile t+1's 6 loads retired; t+2's in flight
    asm volatile("s_waitcnt lgkmcnt(0)" ::: "memory");
    __builtin_amdgcn_sched_barrier(0);
    __builtin_amdgcn_s_setprio(1);
#pragma unroll
    for (int mi = 0; mi < 4; ++mi)
#pragma unroll
      for (int ni = 0; ni < 8; ++ni)
        acc[mi][ni] = __builtin_amdgcn_mfma_f32_16x16x32_f16(af[mi], bf[ni], acc[mi][ni], 0, 0, 0);
    __builtin_amdgcn_s_setprio(0);
    __builtin_amdgcn_s_barrier();
    sl = (sl + 1 == 3) ? 0 : sl + 1;
  }
  vmwait<0>();

  const int fq = g * 4;
  if constexpr (MODE == 1) {
    f16* Cp = (f16*)C;
#pragma unroll
    for (int mi = 0; mi < 4; ++mi)
#pragma unroll
      for (int ni = 0; ni < 8; ++ni)
#pragma unroll
        for (int i = 0; i < 4; ++i) {
          const int row = m0 + wm * 64 + mi * 16 + fq + i;
          const int col = n0 + wn * 128 + ni * 16 + fr;
          Cp[(long)row * N + col] = (f16)(acc[mi][ni][i] * 0.03125f);
        }
  } else if constexpr (MODE == 5) {
    // pipelined mask prefetch: load mi+1's 32 mask values while exp/storing mi
    const float* mk = xtra + (long)bz * sC;
    f16* Cp = (f16*)C + (long)bz * sC;
    float mb0[32], mb1[32];
#pragma unroll
    for (int ni = 0; ni < 8; ++ni)
#pragma unroll
      for (int i = 0; i < 4; ++i) {
        const int row = m0 + wm * 64 + fq + i;
        const int col = n0 + wn * 128 + ni * 16 + fr;
        mb0[ni * 4 + i] = mk[(long)row * N + col];
      }
#pragma unroll
    for (int mi = 0; mi < 4; ++mi) {
      float* curb = (mi & 1) ? mb1 : mb0;
      float* nxtb = (mi & 1) ? mb0 : mb1;
      if (mi < 3) {
#pragma unroll
        for (int ni = 0; ni < 8; ++ni)
#pragma unroll
          for (int i = 0; i < 4; ++i) {
            const int row = m0 + wm * 64 + (mi + 1) * 16 + fq + i;
            const int col = n0 + wn * 128 + ni * 16 + fr;
            nxtb[ni * 4 + i] = mk[(long)row * N + col];
          }
      }
#pragma unroll
      for (int ni = 0; ni < 8; ++ni)
#pragma unroll
        for (int i = 0; i < 4; ++i) {
          const int row = m0 + wm * 64 + mi * 16 + fq + i;
          const int col = n0 + wn * 128 + ni * 16 + fr;
          Cp[(long)row * N + col] = (f16)__expf(acc[mi][ni][i] + curb[ni * 4 + i]);
        }
    }
  } else {
    // MODE 6: finish rowsums (reduce over g: xor 16,32; gather per-output-row) and divide.
    float* Cp = (float*)C + (long)bz * sC;
#pragma unroll
    for (int mi = 0; mi < 4; ++mi) {
      float sv = pr[mi];
      sv += __shfl_xor(sv, 16);
      sv += __shfl_xor(sv, 32);
#pragma unroll
      for (int i = 0; i < 4; ++i) {
        const float rsv = __shfl(sv, fq + i);
        const float inv = 1.0f / rsv;
        const int row = m0 + wm * 64 + mi * 16 + fq + i;
#pragma unroll
        for (int ni = 0; ni < 8; ++ni) {
          const int col = n0 + wn * 128 + ni * 16 + fr;
          Cp[(long)row * N + col] = acc[mi][ni][i] * inv;
        }
      }
    }
  }
}

extern "C" void kernel_launch(void* const* d_in, const int* in_sizes, int n_in,
                              void* d_out, int out_size, void* d_ws, size_t ws_size,
                              hipStream_t stream) {
  const float* x1 = (const float*)d_in[0];
  const float* x2 = (const float*)d_in[1];
  const float* x3 = (const float*)d_in[2];
  const float* mask = (const float*)d_in[3];
  const float* Wq = (const float*)d_in[4];
  const float* Wk = (const float*)d_in[5];
  const float* Wv = (const float*)d_in[6];

  const long nx = (long)B_ * S_ * D_;
  const long nw = (long)H_ * D_;
  const long nqkv = (long)B_ * S_ * H_;
  const long nsc = (long)B_ * S_ * S_;

  char* ws = (char*)d_ws;
  f16* x1h = (f16*)ws; ws += nx * 2;
  f16* x2h = (f16*)ws; ws += nx * 2;     // scores B-operand
  f16* x3h = (f16*)ws; ws += nx * 2;
  f16* wvh = (f16*)ws; ws += nw * 2;
  f16* wqT = (f16*)ws; ws += nw * 2;
  f16* wkT = (f16*)ws; ws += nw * 2;
  f16* mt  = (f16*)ws; ws += nw * 2;     // Mt[e][d] = sum_h Wk[h][e] Wq[h][d]
  f16* qh  = (f16*)ws; ws += nqkv * 2;   // Qeff = x1 * Mt^T * scale
  f16* vth = (f16*)ws; ws += nqkv * 2;   // V^T [b][h][s]
  f16* sc  = (f16*)ws; ws += nsc * 2;    // U = exp(scores + mask), f16

  prep<<<dim3(8448), 256, 0, stream>>>(x1, x2, x3, Wv, Wq, Wk,
                                       x1h, x2h, x3h, wvh, wqT, wkT);

  const dim3 blk(256);
  // union: V^T projection (256 blocks) + Mt (64 blocks)
  vt_mt<<<dim3(320), blk, 0, stream>>>(x3h, wvh, vth, wkT, wqT, mt);
  // Qeff = x1h * Mt^T * scale : wide tile, 64 x 4 = 256 blocks
  gemm128w<1><<<dim3(256), blk, 0, stream>>>(x1h, mt, qh, nullptr, 1024, 1024,
                                             0, 0, 0, 64, 4);
  // U[b] = exp(Qeff[b] x2[b]^T + mask[b]) -> f16 : 16 x 8 x 4 = 512 blocks
  gemm128w<5><<<dim3(512), blk, 0, stream>>>(qh, x2h, sc, mask, 2048, 1024,
                                             (long)S_ * H_, (long)S_ * D_, (long)S_ * S_, 16, 8);
  // out[b] = (U[b] (V^T[b])^T) / rowsum(U) : 16 x 4 x 4 = 256 blocks, rowsum in-kernel
  gemm128w<6><<<dim3(256), blk, 0, stream>>>(sc, vth, d_out, nullptr, 1024, 2048,
                                             (long)S_ * S_, (long)S_ * H_, (long)S_ * H_, 16, 4);
}